// Round 4
// baseline (1003.554 us; speedup 1.0000x reference)
//
#include <hip/hip_runtime.h>

#define NN   102400
#define EE   819200
#define GG   512
#define NPG  200
#define DD   128
#define TT   64
#define BB   8
#define LL   4
#define ECAP 2304

typedef unsigned int uint;

static __device__ __forceinline__ float wave_sum64(float v) {
#pragma unroll
    for (int off = 32; off > 0; off >>= 1) v += __shfl_xor(v, off, 64);
    return v;
}

// ---------------- CSR build (sort edges by dst node) ----------------

__global__ void k_ncount(const int* __restrict__ dst, int* __restrict__ cnt) {
    int e = blockIdx.x * blockDim.x + threadIdx.x;
    if (e < EE) atomicAdd(&cnt[dst[e]], 1);
}

__global__ __launch_bounds__(64) void k_gsum(const int* __restrict__ cnt,
                                             int* __restrict__ gcnt) {
    int g = blockIdx.x, t = threadIdx.x;
    int s = 0;
    for (int i = t; i < NPG; i += 64) s += cnt[g * NPG + i];
#pragma unroll
    for (int off = 32; off > 0; off >>= 1) s += __shfl_xor(s, off, 64);
    if (t == 0) gcnt[g] = s;
}

__global__ void k_gprefix(const int* __restrict__ gcnt, int* __restrict__ gbase) {
    __shared__ int sm[GG];
    int t = threadIdx.x;
    int c = gcnt[t];
    sm[t] = c;
    __syncthreads();
    for (int d = 1; d < GG; d <<= 1) {
        int v = (t >= d) ? sm[t - d] : 0;
        __syncthreads();
        sm[t] += v;
        __syncthreads();
    }
    gbase[t] = sm[t] - c;
    if (t == GG - 1) gbase[GG] = sm[t];
}

__global__ __launch_bounds__(256) void k_nscan(const int* __restrict__ cnt,
                                               const int* __restrict__ gbase,
                                               int* __restrict__ node_off,
                                               int* __restrict__ cursorN) {
    int g = blockIdx.x, t = threadIdx.x;
    __shared__ int sm[256];
    int c = (t < NPG) ? cnt[g * NPG + t] : 0;
    sm[t] = c;
    __syncthreads();
    for (int d = 1; d < 256; d <<= 1) {
        int v = (t >= d) ? sm[t - d] : 0;
        __syncthreads();
        sm[t] += v;
        __syncthreads();
    }
    if (t < NPG) {
        int off = gbase[g] + sm[t] - c;
        node_off[g * NPG + t] = off;
        cursorN[g * NPG + t] = off;
    }
    if (g == GG - 1 && t == 0) node_off[NN] = gbase[GG];
}

__global__ void k_escatter(const int* __restrict__ src, const int* __restrict__ dst,
                           const int* __restrict__ cnt, int* __restrict__ cursorN,
                           uint2* __restrict__ epackN) {
    int e = blockIdx.x * blockDim.x + threadIdx.x;
    if (e >= EE) return;
    int s = src[e], d = dst[e];
    int pos = atomicAdd(&cursorN[d], 1);
    float w = rsqrtf((float)(cnt[s] + 1)) * rsqrtf((float)(cnt[d] + 1));
    epackN[pos] = make_uint2((uint)(s % NPG), __float_as_uint(w));
}

// ---------------- fully fused GCN (3 layers + readout + PE), 1 block per graph ----

// aggregation over in-edges of node i, all-LDS (with rare global tail)
#define AGG_NODE(SRCBUF, i)                                                \
    float acc = SRCBUF[(i) * 64 + j] * dinv2[i];                           \
    {                                                                      \
        int e0 = noff[i] - ebase, e1 = noff[(i) + 1] - ebase;              \
        int eC = e1 < ECAP ? e1 : ECAP;                                    \
        for (int e = e0; e < eC; ++e) {                                    \
            uint2 ed = eb[e];                                              \
            acc += SRCBUF[ed.x * 64 + j] * __uint_as_float(ed.y);          \
        }                                                                  \
        for (int e = (e0 > ECAP ? e0 : ECAP); e < e1; ++e) {               \
            uint2 ed = eg[e];                                              \
            acc += SRCBUF[ed.x * 64 + j] * __uint_as_float(ed.y);          \
        }                                                                  \
    }

__global__ __launch_bounds__(256) void k_gcn_all(
    const float* __restrict__ x, const float* __restrict__ W1,
    const float* __restrict__ gb1, const float* __restrict__ ln1g,
    const float* __restrict__ ln1b, const float* __restrict__ W2,
    const float* __restrict__ gb2, const float* __restrict__ ln2g,
    const float* __restrict__ ln2b, const float* __restrict__ W3,
    const float* __restrict__ b3, const int* __restrict__ cnt,
    const int* __restrict__ node_off, const uint2* __restrict__ epackN,
    float* __restrict__ seqT) {
    int g = blockIdx.x;
    __shared__ float hs[NPG * 64];    // 51.2 KB
    __shared__ float ts[NPG * 64];    // 51.2 KB
    __shared__ float ws[64 * 64];     // 16 KB (staged W2 / W3-half)
    __shared__ uint2 eb[ECAP];        // 18.4 KB
    __shared__ float2 xs[NPG];        // 1.6 KB
    __shared__ float dinv2[NPG];
    __shared__ int noff[NPG + 1];
    __shared__ float red[4][64];
    int tid = threadIdx.x, j = tid & 63, wid = tid >> 6;

    for (int i = tid; i <= NPG; i += 256) noff[i] = node_off[g * NPG + i];
    for (int i = tid; i < NPG; i += 256) {
        xs[i] = ((const float2*)x)[g * NPG + i];
        dinv2[i] = 1.f / (float)(cnt[g * NPG + i] + 1);
    }
    __syncthreads();
    int ebase = noff[0];
    int ecnt = noff[NPG] - ebase;
    const uint2* eg = epackN + ebase;
    int ecap = ecnt < ECAP ? ecnt : ECAP;
    for (int i = tid; i < ecap; i += 256) eb[i] = eg[i];

    // ---- layer 1: transform x(2)->64 into ts ----
    float w0 = W1[j], w1 = W1[64 + j];
    for (int i = wid; i < NPG; i += 4) {
        float2 xv = xs[i];
        ts[i * 64 + j] = xv.x * w0 + xv.y * w1;
    }
    __syncthreads();
    // agg + bias/relu/LN -> hs
    for (int i = wid; i < NPG; i += 4) {
        AGG_NODE(ts, i)
        float u = fmaxf(acc + gb1[j], 0.f);
        float mean = wave_sum64(u) * (1.f / 64.f);
        float dv = u - mean;
        float var = wave_sum64(dv * dv) * (1.f / 64.f);
        hs[i * 64 + j] = dv * rsqrtf(var + 1e-5f) * ln1g[j] + ln1b[j];
    }
    __syncthreads();

    // ---- layer 2: hs @ W2 -> ts, agg -> hs ----
    for (int i = tid; i < 1024; i += 256) ((float4*)ws)[i] = ((const float4*)W2)[i];
    __syncthreads();
    {
        float wreg[64];
#pragma unroll
        for (int k = 0; k < 64; ++k) wreg[k] = ws[k * 64 + j];
        for (int i = wid; i < NPG; i += 4) {
            const float4* hrow = (const float4*)&hs[i * 64];
            float a0 = 0.f, a1 = 0.f;
#pragma unroll
            for (int k4 = 0; k4 < 16; k4 += 2) {
                float4 h0 = hrow[k4], h1 = hrow[k4 + 1];
                a0 += h0.x * wreg[4 * k4] + h0.y * wreg[4 * k4 + 1] +
                      h0.z * wreg[4 * k4 + 2] + h0.w * wreg[4 * k4 + 3];
                a1 += h1.x * wreg[4 * k4 + 4] + h1.y * wreg[4 * k4 + 5] +
                      h1.z * wreg[4 * k4 + 6] + h1.w * wreg[4 * k4 + 7];
            }
            ts[i * 64 + j] = a0 + a1;
        }
    }
    __syncthreads();
    for (int i = wid; i < NPG; i += 4) {
        AGG_NODE(ts, i)
        float u = fmaxf(acc + gb2[j], 0.f);
        float mean = wave_sum64(u) * (1.f / 64.f);
        float dv = u - mean;
        float var = wave_sum64(dv * dv) * (1.f / 64.f);
        hs[i * 64 + j] = dv * rsqrtf(var + 1e-5f) * ln2g[j] + ln2b[j];
    }

    // ---- layer 3 (64->128 in two 64-halves) + mean readout + PE ----
    for (int sl = 0; sl < 2; ++sl) {
        __syncthreads();
        // stage W3 half: ws[k*64 + c*4 ..] = W3[k*128 + sl*64 + c*4 ..]
        const float4* W3h = (const float4*)(W3 + sl * 64);
        for (int idx = tid; idx < 1024; idx += 256) {
            int k = idx >> 4, c = idx & 15;
            ((float4*)ws)[idx] = W3h[k * 32 + c];
        }
        __syncthreads();
        {
            float wreg[64];
#pragma unroll
            for (int k = 0; k < 64; ++k) wreg[k] = ws[k * 64 + j];
            for (int i = wid; i < NPG; i += 4) {
                const float4* hrow = (const float4*)&hs[i * 64];
                float a0 = 0.f, a1 = 0.f;
#pragma unroll
                for (int k4 = 0; k4 < 16; k4 += 2) {
                    float4 h0 = hrow[k4], h1 = hrow[k4 + 1];
                    a0 += h0.x * wreg[4 * k4] + h0.y * wreg[4 * k4 + 1] +
                          h0.z * wreg[4 * k4 + 2] + h0.w * wreg[4 * k4 + 3];
                    a1 += h1.x * wreg[4 * k4 + 4] + h1.y * wreg[4 * k4 + 5] +
                          h1.z * wreg[4 * k4 + 6] + h1.w * wreg[4 * k4 + 7];
                }
                ts[i * 64 + j] = a0 + a1;
            }
        }
        __syncthreads();
        float rsum = 0.f;
        for (int i = wid; i < NPG; i += 4) {
            AGG_NODE(ts, i)
            rsum += acc;
        }
        red[wid][j] = rsum;
        __syncthreads();
        if (tid < 64) {
            int d = sl * 64 + j;
            float val = (red[0][j] + red[1][j] + red[2][j] + red[3][j]) * (1.f / NPG) + b3[d];
            float freq = expf((float)(d & ~1) * (-9.210340371976184f / 128.f));
            float ang = (float)(g & (TT - 1)) * freq;
            val += (d & 1) ? cosf(ang) : sinf(ang);
            seqT[d * GG + g] = val;
        }
    }
}

// ---------------- Transformer (transposed activations: [feat][512]) ----------------

template <int K, bool RELU, bool RES>
__global__ __launch_bounds__(128) void k_gemmT(
    const float* __restrict__ AT, const float* __restrict__ W,
    const float* __restrict__ bias, const float* __restrict__ resP,
    float* __restrict__ C) {
    int o = blockIdx.x, t = threadIdx.x;
    __shared__ float ws[K];
    for (int k = t; k < K; k += 128) ws[k] = W[o * K + k];
    __syncthreads();
    const float4* A4 = (const float4*)AT;
    float4 acc = make_float4(0.f, 0.f, 0.f, 0.f);
#pragma unroll 8
    for (int k = 0; k < K; ++k) {
        float w = ws[k];
        float4 a = A4[k * 128 + t];
        acc.x += a.x * w; acc.y += a.y * w; acc.z += a.z * w; acc.w += a.w * w;
    }
    float bv = bias[o];
    acc.x += bv; acc.y += bv; acc.z += bv; acc.w += bv;
    if (RELU) {
        acc.x = fmaxf(acc.x, 0.f); acc.y = fmaxf(acc.y, 0.f);
        acc.z = fmaxf(acc.z, 0.f); acc.w = fmaxf(acc.w, 0.f);
    }
    if (RES) {
        float4 r = ((const float4*)resP)[o * 128 + t];
        acc.x += r.x; acc.y += r.y; acc.z += r.z; acc.w += r.w;
    }
    ((float4*)C)[o * 128 + t] = acc;
}

__global__ __launch_bounds__(64) void k_attnT(const float* __restrict__ qkvT,
                                              float* __restrict__ aT) {
    int b = blockIdx.x >> 2, h = blockIdx.x & 3;
    int t = threadIdx.x;
    __shared__ float Ks[32][TT], Vs[32][TT];
    __shared__ float sp[TT][TT + 1];
    int col = b * TT + t;
#pragma unroll
    for (int dh = 0; dh < 32; ++dh) {
        Ks[dh][t] = qkvT[(DD + h * 32 + dh) * GG + col];
        Vs[dh][t] = qkvT[(2 * DD + h * 32 + dh) * GG + col];
    }
    float q[32];
#pragma unroll
    for (int dh = 0; dh < 32; ++dh) q[dh] = qkvT[(h * 32 + dh) * GG + col];
    __syncthreads();
    const float scale = 0.17677669529663687f;  // 1/sqrt(32)
    for (int jj = 0; jj < TT; ++jj) {
        float a = 0.f;
#pragma unroll
        for (int dh = 0; dh < 32; ++dh) a += q[dh] * Ks[dh][jj];
        sp[t][jj] = a * scale;
    }
    float mx = -1e30f;
    for (int jj = 0; jj < TT; ++jj) mx = fmaxf(mx, sp[t][jj]);
    float ssum = 0.f;
    for (int jj = 0; jj < TT; ++jj) {
        float e2 = expf(sp[t][jj] - mx);
        sp[t][jj] = e2;
        ssum += e2;
    }
    float inv = 1.f / ssum;
    float o[32];
#pragma unroll
    for (int dh = 0; dh < 32; ++dh) o[dh] = 0.f;
    for (int jj = 0; jj < TT; ++jj) {
        float s = sp[t][jj] * inv;
#pragma unroll
        for (int dh = 0; dh < 32; ++dh) o[dh] += s * Vs[dh][jj];
    }
#pragma unroll
    for (int dh = 0; dh < 32; ++dh) aT[(h * 32 + dh) * GG + col] = o[dh];
}

__global__ void k_lnT(float* __restrict__ S, const float* __restrict__ g,
                      const float* __restrict__ bl) {
    int r = blockIdx.x * blockDim.x + threadIdx.x;  // one lane per row
    float sum = 0.f, sq = 0.f;
    for (int d = 0; d < DD; ++d) {
        float v = S[d * GG + r];
        sum += v;
        sq += v * v;
    }
    float mean = sum * (1.f / DD);
    float var = sq * (1.f / DD) - mean * mean;
    float rstd = rsqrtf(var + 1e-5f);
    for (int d = 0; d < DD; ++d) {
        float v = S[d * GG + r];
        S[d * GG + r] = (v - mean) * rstd * g[d] + bl[d];
    }
}

__global__ __launch_bounds__(128) void k_headT(
    const float* __restrict__ seqT, const float* __restrict__ W1,
    const float* __restrict__ b1, const float* __restrict__ W2,
    const float* __restrict__ b2, float* __restrict__ out) {
    int b = blockIdx.x, t = threadIdx.x;
    __shared__ float pooled[DD];
    __shared__ float hid[64];
    const float4* row = (const float4*)(seqT + t * GG + b * TT);
    float4 s4 = make_float4(0.f, 0.f, 0.f, 0.f);
#pragma unroll
    for (int i = 0; i < 16; ++i) {
        float4 v = row[i];
        s4.x += v.x; s4.y += v.y; s4.z += v.z; s4.w += v.w;
    }
    pooled[t] = (s4.x + s4.y + s4.z + s4.w) * (1.f / TT);
    __syncthreads();
    if (t < 64) {
        float a = b1[t];
        const float* wr = W1 + t * DD;
        for (int k = 0; k < DD; ++k) a += pooled[k] * wr[k];
        hid[t] = fmaxf(a, 0.f);
    }
    __syncthreads();
    if (t < 2) {
        float a = b2[t];
        const float* wr = W2 + t * 64;
        for (int k = 0; k < 64; ++k) a += hid[k] * wr[k];
        out[b * 2 + t] = a;
    }
}

// ---------------- host ----------------

extern "C" void kernel_launch(void* const* d_in, const int* in_sizes, int n_in,
                              void* d_out, int out_size, void* d_ws, size_t ws_size,
                              hipStream_t stream) {
    const float* x     = (const float*)d_in[0];
    const int*   esrc  = (const int*)d_in[1];
    const int*   edst  = (const int*)d_in[2];
    const float* gW1   = (const float*)d_in[4];
    const float* gb1   = (const float*)d_in[5];
    const float* ln1g  = (const float*)d_in[6];
    const float* ln1b  = (const float*)d_in[7];
    const float* gW2   = (const float*)d_in[8];
    const float* gb2   = (const float*)d_in[9];
    const float* ln2g  = (const float*)d_in[10];
    const float* ln2b  = (const float*)d_in[11];
    const float* gW3   = (const float*)d_in[12];
    const float* gb3   = (const float*)d_in[13];
    const float* tWqkv = (const float*)d_in[14];
    const float* tbqkv = (const float*)d_in[15];
    const float* tWo   = (const float*)d_in[16];
    const float* tbo   = (const float*)d_in[17];
    const float* tg1   = (const float*)d_in[18];
    const float* tb1   = (const float*)d_in[19];
    const float* tg2   = (const float*)d_in[20];
    const float* tb2   = (const float*)d_in[21];
    const float* tWf1  = (const float*)d_in[22];
    const float* tbf1  = (const float*)d_in[23];
    const float* tWf2  = (const float*)d_in[24];
    const float* tbf2  = (const float*)d_in[25];
    const float* hW1   = (const float*)d_in[26];
    const float* hb1   = (const float*)d_in[27];
    const float* hW2   = (const float*)d_in[28];
    const float* hb2   = (const float*)d_in[29];
    float* out = (float*)d_out;

    int* cntN     = (int*)d_ws;              // NN
    int* gcnt     = cntN + NN;               // 512
    int* gbase    = gcnt + GG;               // 513 (pad 516)
    int* node_off = gbase + 516;             // NN+1 (pad NN+4)
    int* cursorN  = node_off + NN + 4;       // NN
    uint2* epackN = (uint2*)(cursorN + NN);  // EE
    float* seqT = (float*)(epackN + EE);     // 128*512
    float* qkvT = seqT + DD * GG;            // 384*512
    float* aT   = qkvT + 3 * DD * GG;        // 128*512
    float* f1T  = aT + DD * GG;              // 512*512

    const int BS = 256;
    // CSR build
    hipMemsetAsync(cntN, 0, NN * sizeof(int), stream);
    k_ncount<<<EE / BS, BS, 0, stream>>>(edst, cntN);
    k_gsum<<<GG, 64, 0, stream>>>(cntN, gcnt);
    k_gprefix<<<1, GG, 0, stream>>>(gcnt, gbase);
    k_nscan<<<GG, BS, 0, stream>>>(cntN, gbase, node_off, cursorN);
    k_escatter<<<EE / BS, BS, 0, stream>>>(esrc, edst, cntN, cursorN, epackN);

    // fully fused GCN + readout + PE
    k_gcn_all<<<GG, BS, 0, stream>>>(x, gW1, gb1, ln1g, ln1b, gW2, gb2, ln2g, ln2b,
                                     gW3, gb3, cntN, node_off, epackN, seqT);

    // Transformer (transposed activations)
    for (int l = 0; l < LL; l++) {
        k_gemmT<128, false, false><<<384, 128, 0, stream>>>(
            seqT, tWqkv + (size_t)l * 384 * 128, tbqkv + l * 384, nullptr, qkvT);
        k_attnT<<<BB * 4, TT, 0, stream>>>(qkvT, aT);
        k_gemmT<128, false, true><<<128, 128, 0, stream>>>(
            aT, tWo + (size_t)l * 128 * 128, tbo + l * 128, seqT, seqT);
        k_lnT<<<2, 256, 0, stream>>>(seqT, tg1 + l * 128, tb1 + l * 128);
        k_gemmT<128, true, false><<<512, 128, 0, stream>>>(
            seqT, tWf1 + (size_t)l * 512 * 128, tbf1 + l * 512, nullptr, f1T);
        k_gemmT<512, false, true><<<128, 128, 0, stream>>>(
            f1T, tWf2 + (size_t)l * 128 * 512, tbf2 + l * 128, seqT, seqT);
        k_lnT<<<2, 256, 0, stream>>>(seqT, tg2 + l * 128, tb2 + l * 128);
    }

    // head
    k_headT<<<BB, 128, 0, stream>>>(seqT, hW1, hb1, hW2, hb2, out);
}

// Round 5
// 715.495 us; speedup vs baseline: 1.4026x; 1.4026x over previous
//
#include <hip/hip_runtime.h>

#define NN   102400
#define EE   819200
#define GG   512
#define NPG  200
#define DD   128
#define TT   64
#define BB   8
#define LL   4
#define ECAP 2304

typedef unsigned int uint;

static __device__ __forceinline__ float wave_sum64(float v) {
#pragma unroll
    for (int off = 32; off > 0; off >>= 1) v += __shfl_xor(v, off, 64);
    return v;
}

// ---------------- CSR build (sort edges by dst node) ----------------

__global__ void k_ncount(const int* __restrict__ dst, int* __restrict__ cnt) {
    int e = blockIdx.x * blockDim.x + threadIdx.x;
    if (e < EE) atomicAdd(&cnt[dst[e]], 1);
}

__global__ __launch_bounds__(64) void k_gsum(const int* __restrict__ cnt,
                                             int* __restrict__ gcnt) {
    int g = blockIdx.x, t = threadIdx.x;
    int s = 0;
    for (int i = t; i < NPG; i += 64) s += cnt[g * NPG + i];
#pragma unroll
    for (int off = 32; off > 0; off >>= 1) s += __shfl_xor(s, off, 64);
    if (t == 0) gcnt[g] = s;
}

__global__ void k_gprefix(const int* __restrict__ gcnt, int* __restrict__ gbase) {
    __shared__ int sm[GG];
    int t = threadIdx.x;
    int c = gcnt[t];
    sm[t] = c;
    __syncthreads();
    for (int d = 1; d < GG; d <<= 1) {
        int v = (t >= d) ? sm[t - d] : 0;
        __syncthreads();
        sm[t] += v;
        __syncthreads();
    }
    gbase[t] = sm[t] - c;
    if (t == GG - 1) gbase[GG] = sm[t];
}

__global__ __launch_bounds__(256) void k_nscan(const int* __restrict__ cnt,
                                               const int* __restrict__ gbase,
                                               int* __restrict__ node_off,
                                               int* __restrict__ cursorN) {
    int g = blockIdx.x, t = threadIdx.x;
    __shared__ int sm[256];
    int c = (t < NPG) ? cnt[g * NPG + t] : 0;
    sm[t] = c;
    __syncthreads();
    for (int d = 1; d < 256; d <<= 1) {
        int v = (t >= d) ? sm[t - d] : 0;
        __syncthreads();
        sm[t] += v;
        __syncthreads();
    }
    if (t < NPG) {
        int off = gbase[g] + sm[t] - c;
        node_off[g * NPG + t] = off;
        cursorN[g * NPG + t] = off;
    }
    if (g == GG - 1 && t == 0) node_off[NN] = gbase[GG];
}

__global__ void k_escatter(const int* __restrict__ src, const int* __restrict__ dst,
                           const int* __restrict__ cnt, int* __restrict__ cursorN,
                           uint2* __restrict__ epackN) {
    int e = blockIdx.x * blockDim.x + threadIdx.x;
    if (e >= EE) return;
    int s = src[e], d = dst[e];
    int pos = atomicAdd(&cursorN[d], 1);
    float w = rsqrtf((float)(cnt[s] + 1)) * rsqrtf((float)(cnt[d] + 1));
    epackN[pos] = make_uint2((uint)(s % NPG), __float_as_uint(w));
}

// ---------------- GCN ----------------

// layer 1: agg x (2-wide, thread-per-node) then 2->64 transform + bias/relu/LN
__global__ __launch_bounds__(256) void k_gcn1(
    const float* __restrict__ x, const float* __restrict__ W1,
    const float* __restrict__ gb1, const float* __restrict__ lng,
    const float* __restrict__ lnb, const int* __restrict__ cnt,
    const int* __restrict__ node_off, const uint2* __restrict__ epackN,
    float* __restrict__ hout) {
    int g = blockIdx.x;
    __shared__ float2 xs[NPG];
    __shared__ float2 axs[NPG];
    __shared__ uint2 eb[ECAP];
    __shared__ int noff[NPG + 1];
    __shared__ float dinv2[NPG];
    int tid = threadIdx.x, j = tid & 63, wid = tid >> 6;
    for (int i = tid; i <= NPG; i += 256) noff[i] = node_off[g * NPG + i];
    for (int i = tid; i < NPG; i += 256) {
        xs[i] = ((const float2*)x)[g * NPG + i];
        dinv2[i] = 1.f / (float)(cnt[g * NPG + i] + 1);
    }
    __syncthreads();
    int ebase = noff[0];
    int ecnt = noff[NPG] - ebase;
    const uint2* eg = epackN + ebase;
    int ecap = ecnt < ECAP ? ecnt : ECAP;
    for (int i = tid; i < ecap; i += 256) eb[i] = eg[i];
    __syncthreads();
    // phase A: 2-wide aggregation, one thread per node
    if (tid < NPG) {
        int i = tid;
        float2 a;
        a.x = xs[i].x * dinv2[i];
        a.y = xs[i].y * dinv2[i];
        int e0 = noff[i] - ebase, e1 = noff[i + 1] - ebase;
        int eC = e1 < ECAP ? e1 : ECAP;
        for (int e = e0; e < eC; ++e) {
            uint2 ed = eb[e];
            float w = __uint_as_float(ed.y);
            float2 xe = xs[ed.x];
            a.x += xe.x * w;
            a.y += xe.y * w;
        }
        for (int e = (e0 > ECAP ? e0 : ECAP); e < e1; ++e) {
            uint2 ed = eg[e];
            float w = __uint_as_float(ed.y);
            float2 xe = xs[ed.x];
            a.x += xe.x * w;
            a.y += xe.y * w;
        }
        axs[i] = a;
    }
    __syncthreads();
    // phase B: transform + LN, wave per node
    float w0 = W1[j], w1 = W1[64 + j];
    for (int i = wid; i < NPG; i += 4) {
        float2 a = axs[i];
        float u = fmaxf(a.x * w0 + a.y * w1 + gb1[j], 0.f);
        float mean = wave_sum64(u) * (1.f / 64.f);
        float dv = u - mean;
        float var = wave_sum64(dv * dv) * (1.f / 64.f);
        hout[(g * NPG + i) * 64 + j] = dv * rsqrtf(var + 1e-5f) * lng[j] + lnb[j];
    }
}

// tiled 64->64 dense transform: 64 nodes per block, W in registers
__global__ __launch_bounds__(256) void k_lin64(
    const float* __restrict__ in, const float* __restrict__ W,
    float* __restrict__ out) {
    int nb = blockIdx.x;  // 1600 blocks x 64 nodes
    __shared__ float hs[64 * 64];
    __shared__ float ws[64 * 64];
    int tid = threadIdx.x, j = tid & 63, wid = tid >> 6;
    const float4* in4 = (const float4*)(in + (size_t)nb * 64 * 64);
    for (int i = tid; i < 1024; i += 256) {
        ((float4*)hs)[i] = in4[i];
        ((float4*)ws)[i] = ((const float4*)W)[i];
    }
    __syncthreads();
    float wreg[64];
#pragma unroll
    for (int k = 0; k < 64; ++k) wreg[k] = ws[k * 64 + j];
    float* ob = out + (size_t)nb * 64 * 64;
    for (int i = wid; i < 64; i += 4) {
        const float4* hrow = (const float4*)&hs[i * 64];
        float a0 = 0.f, a1 = 0.f;
#pragma unroll
        for (int k4 = 0; k4 < 16; k4 += 2) {
            float4 h0 = hrow[k4], h1 = hrow[k4 + 1];
            a0 += h0.x * wreg[4 * k4] + h0.y * wreg[4 * k4 + 1] +
                  h0.z * wreg[4 * k4 + 2] + h0.w * wreg[4 * k4 + 3];
            a1 += h1.x * wreg[4 * k4 + 4] + h1.y * wreg[4 * k4 + 5] +
                  h1.z * wreg[4 * k4 + 6] + h1.w * wreg[4 * k4 + 7];
        }
        ob[i * 64 + j] = a0 + a1;
    }
}

// 64-wide aggregation + bias/relu/LN (layer 2). Feature slice in LDS, edges from global.
__global__ __launch_bounds__(256) void k_agg_ln(
    const float* __restrict__ t_all, const int* __restrict__ cnt,
    const int* __restrict__ node_off, const uint2* __restrict__ epackN,
    const float* __restrict__ gb, const float* __restrict__ lng,
    const float* __restrict__ lnb, float* __restrict__ hout) {
    int g = blockIdx.x;
    __shared__ float ts[NPG * 64];
    __shared__ int noff[NPG + 1];
    __shared__ float dinv2[NPG];
    int tid = threadIdx.x, j = tid & 63, wid = tid >> 6;
    const float4* tg4 = (const float4*)(t_all + (size_t)g * NPG * 64);
    for (int i = tid; i < NPG * 16; i += 256) ((float4*)ts)[i] = tg4[i];
    for (int i = tid; i <= NPG; i += 256) noff[i] = node_off[g * NPG + i];
    for (int i = tid; i < NPG; i += 256) dinv2[i] = 1.f / (float)(cnt[g * NPG + i] + 1);
    __syncthreads();
    const uint2* eg = epackN;
    for (int i = wid; i < NPG; i += 4) {
        float acc = ts[i * 64 + j] * dinv2[i];
        int e0 = noff[i], e1 = noff[i + 1];
        int e = e0;
        for (; e + 1 < e1; e += 2) {
            uint2 ed0 = eg[e], ed1 = eg[e + 1];
            acc += ts[ed0.x * 64 + j] * __uint_as_float(ed0.y);
            acc += ts[ed1.x * 64 + j] * __uint_as_float(ed1.y);
        }
        if (e < e1) {
            uint2 ed = eg[e];
            acc += ts[ed.x * 64 + j] * __uint_as_float(ed.y);
        }
        float u = fmaxf(acc + gb[j], 0.f);
        float mean = wave_sum64(u) * (1.f / 64.f);
        float dv = u - mean;
        float var = wave_sum64(dv * dv) * (1.f / 64.f);
        hout[(g * NPG + i) * 64 + j] = dv * rsqrtf(var + 1e-5f) * lng[j] + lnb[j];
    }
}

// layer-3 aggregation + mean pooling -> pooledT[64][512]
__global__ __launch_bounds__(256) void k_agg_pool(
    const float* __restrict__ t_all, const int* __restrict__ cnt,
    const int* __restrict__ node_off, const uint2* __restrict__ epackN,
    float* __restrict__ pooledT) {
    int g = blockIdx.x;
    __shared__ float ts[NPG * 64];
    __shared__ int noff[NPG + 1];
    __shared__ float dinv2[NPG];
    __shared__ float red[4][64];
    int tid = threadIdx.x, j = tid & 63, wid = tid >> 6;
    const float4* tg4 = (const float4*)(t_all + (size_t)g * NPG * 64);
    for (int i = tid; i < NPG * 16; i += 256) ((float4*)ts)[i] = tg4[i];
    for (int i = tid; i <= NPG; i += 256) noff[i] = node_off[g * NPG + i];
    for (int i = tid; i < NPG; i += 256) dinv2[i] = 1.f / (float)(cnt[g * NPG + i] + 1);
    __syncthreads();
    const uint2* eg = epackN;
    float rsum = 0.f;
    for (int i = wid; i < NPG; i += 4) {
        float acc = ts[i * 64 + j] * dinv2[i];
        int e0 = noff[i], e1 = noff[i + 1];
        int e = e0;
        for (; e + 1 < e1; e += 2) {
            uint2 ed0 = eg[e], ed1 = eg[e + 1];
            acc += ts[ed0.x * 64 + j] * __uint_as_float(ed0.y);
            acc += ts[ed1.x * 64 + j] * __uint_as_float(ed1.y);
        }
        if (e < e1) {
            uint2 ed = eg[e];
            acc += ts[ed.x * 64 + j] * __uint_as_float(ed.y);
        }
        rsum += acc;
    }
    red[wid][j] = rsum;
    __syncthreads();
    if (tid < 64)
        pooledT[j * GG + g] = (red[0][j] + red[1][j] + red[2][j] + red[3][j]) * (1.f / NPG);
}

// pooled(64) @ W3 -> (128) + b3 + PE, writes seqT[d][g]
__global__ __launch_bounds__(512) void k_emb(
    const float* __restrict__ pooledT, const float* __restrict__ W3,
    const float* __restrict__ b3, float* __restrict__ seqT) {
    int d = blockIdx.x, g = threadIdx.x;
    __shared__ float wcol[64];
    if (g < 64) wcol[g] = W3[g * DD + d];
    __syncthreads();
    float acc = b3[d];
#pragma unroll 8
    for (int k = 0; k < 64; ++k) acc += pooledT[k * GG + g] * wcol[k];
    float freq = expf((float)(d & ~1) * (-9.210340371976184f / 128.f));
    float ang = (float)(g & (TT - 1)) * freq;
    acc += (d & 1) ? cosf(ang) : sinf(ang);
    seqT[d * GG + g] = acc;
}

// ---------------- Transformer (transposed activations: [feat][512]) ----------------

template <int K, bool RELU, bool RES>
__global__ __launch_bounds__(128) void k_gemmT(
    const float* __restrict__ AT, const float* __restrict__ W,
    const float* __restrict__ bias, const float* __restrict__ resP,
    float* __restrict__ C) {
    int o = blockIdx.x, t = threadIdx.x;
    __shared__ float ws[K];
    for (int k = t; k < K; k += 128) ws[k] = W[o * K + k];
    __syncthreads();
    const float4* A4 = (const float4*)AT;
    float4 acc = make_float4(0.f, 0.f, 0.f, 0.f);
#pragma unroll 8
    for (int k = 0; k < K; ++k) {
        float w = ws[k];
        float4 a = A4[k * 128 + t];
        acc.x += a.x * w; acc.y += a.y * w; acc.z += a.z * w; acc.w += a.w * w;
    }
    float bv = bias[o];
    acc.x += bv; acc.y += bv; acc.z += bv; acc.w += bv;
    if (RELU) {
        acc.x = fmaxf(acc.x, 0.f); acc.y = fmaxf(acc.y, 0.f);
        acc.z = fmaxf(acc.z, 0.f); acc.w = fmaxf(acc.w, 0.f);
    }
    if (RES) {
        float4 r = ((const float4*)resP)[o * 128 + t];
        acc.x += r.x; acc.y += r.y; acc.z += r.z; acc.w += r.w;
    }
    ((float4*)C)[o * 128 + t] = acc;
}

__global__ __launch_bounds__(64) void k_attnT(const float* __restrict__ qkvT,
                                              float* __restrict__ aT) {
    int b = blockIdx.x >> 2, h = blockIdx.x & 3;
    int t = threadIdx.x;
    __shared__ float Ks[32][TT], Vs[32][TT];
    __shared__ float sp[TT][TT + 1];
    int col = b * TT + t;
#pragma unroll
    for (int dh = 0; dh < 32; ++dh) {
        Ks[dh][t] = qkvT[(DD + h * 32 + dh) * GG + col];
        Vs[dh][t] = qkvT[(2 * DD + h * 32 + dh) * GG + col];
    }
    float q[32];
#pragma unroll
    for (int dh = 0; dh < 32; ++dh) q[dh] = qkvT[(h * 32 + dh) * GG + col];
    __syncthreads();
    const float scale = 0.17677669529663687f;  // 1/sqrt(32)
    for (int jj = 0; jj < TT; ++jj) {
        float a = 0.f;
#pragma unroll
        for (int dh = 0; dh < 32; ++dh) a += q[dh] * Ks[dh][jj];
        sp[t][jj] = a * scale;
    }
    float mx = -1e30f;
    for (int jj = 0; jj < TT; ++jj) mx = fmaxf(mx, sp[t][jj]);
    float ssum = 0.f;
    for (int jj = 0; jj < TT; ++jj) {
        float e2 = expf(sp[t][jj] - mx);
        sp[t][jj] = e2;
        ssum += e2;
    }
    float inv = 1.f / ssum;
    float o[32];
#pragma unroll
    for (int dh = 0; dh < 32; ++dh) o[dh] = 0.f;
    for (int jj = 0; jj < TT; ++jj) {
        float s = sp[t][jj] * inv;
#pragma unroll
        for (int dh = 0; dh < 32; ++dh) o[dh] += s * Vs[dh][jj];
    }
#pragma unroll
    for (int dh = 0; dh < 32; ++dh) aT[(h * 32 + dh) * GG + col] = o[dh];
}

__global__ void k_lnT(float* __restrict__ S, const float* __restrict__ g,
                      const float* __restrict__ bl) {
    int r = blockIdx.x * blockDim.x + threadIdx.x;  // one lane per row
    float sum = 0.f, sq = 0.f;
    for (int d = 0; d < DD; ++d) {
        float v = S[d * GG + r];
        sum += v;
        sq += v * v;
    }
    float mean = sum * (1.f / DD);
    float var = sq * (1.f / DD) - mean * mean;
    float rstd = rsqrtf(var + 1e-5f);
    for (int d = 0; d < DD; ++d) {
        float v = S[d * GG + r];
        S[d * GG + r] = (v - mean) * rstd * g[d] + bl[d];
    }
}

__global__ __launch_bounds__(128) void k_headT(
    const float* __restrict__ seqT, const float* __restrict__ W1,
    const float* __restrict__ b1, const float* __restrict__ W2,
    const float* __restrict__ b2, float* __restrict__ out) {
    int b = blockIdx.x, t = threadIdx.x;
    __shared__ float pooled[DD];
    __shared__ float hid[64];
    const float4* row = (const float4*)(seqT + t * GG + b * TT);
    float4 s4 = make_float4(0.f, 0.f, 0.f, 0.f);
#pragma unroll
    for (int i = 0; i < 16; ++i) {
        float4 v = row[i];
        s4.x += v.x; s4.y += v.y; s4.z += v.z; s4.w += v.w;
    }
    pooled[t] = (s4.x + s4.y + s4.z + s4.w) * (1.f / TT);
    __syncthreads();
    if (t < 64) {
        float a = b1[t];
        const float* wr = W1 + t * DD;
        for (int k = 0; k < DD; ++k) a += pooled[k] * wr[k];
        hid[t] = fmaxf(a, 0.f);
    }
    __syncthreads();
    if (t < 2) {
        float a = b2[t];
        const float* wr = W2 + t * 64;
        for (int k = 0; k < 64; ++k) a += hid[k] * wr[k];
        out[b * 2 + t] = a;
    }
}

// ---------------- host ----------------

extern "C" void kernel_launch(void* const* d_in, const int* in_sizes, int n_in,
                              void* d_out, int out_size, void* d_ws, size_t ws_size,
                              hipStream_t stream) {
    const float* x     = (const float*)d_in[0];
    const int*   esrc  = (const int*)d_in[1];
    const int*   edst  = (const int*)d_in[2];
    const float* gW1   = (const float*)d_in[4];
    const float* gb1   = (const float*)d_in[5];
    const float* ln1g  = (const float*)d_in[6];
    const float* ln1b  = (const float*)d_in[7];
    const float* gW2   = (const float*)d_in[8];
    const float* gb2   = (const float*)d_in[9];
    const float* ln2g  = (const float*)d_in[10];
    const float* ln2b  = (const float*)d_in[11];
    const float* gW3   = (const float*)d_in[12];
    const float* gb3   = (const float*)d_in[13];
    const float* tWqkv = (const float*)d_in[14];
    const float* tbqkv = (const float*)d_in[15];
    const float* tWo   = (const float*)d_in[16];
    const float* tbo   = (const float*)d_in[17];
    const float* tg1   = (const float*)d_in[18];
    const float* tb1   = (const float*)d_in[19];
    const float* tg2   = (const float*)d_in[20];
    const float* tb2   = (const float*)d_in[21];
    const float* tWf1  = (const float*)d_in[22];
    const float* tbf1  = (const float*)d_in[23];
    const float* tWf2  = (const float*)d_in[24];
    const float* tbf2  = (const float*)d_in[25];
    const float* hW1   = (const float*)d_in[26];
    const float* hb1   = (const float*)d_in[27];
    const float* hW2   = (const float*)d_in[28];
    const float* hb2   = (const float*)d_in[29];
    float* out = (float*)d_out;

    int* cntN     = (int*)d_ws;              // NN
    int* gcnt     = cntN + NN;               // 512
    int* gbase    = gcnt + GG;               // 513 (pad 516)
    int* node_off = gbase + 516;             // NN+1 (pad NN+4)
    int* cursorN  = node_off + NN + 4;       // NN
    uint2* epackN = (uint2*)(cursorN + NN);  // EE
    float* bufA = (float*)(epackN + EE);     // NN*64
    float* bufB = bufA + (size_t)NN * 64;    // NN*64
    float* pooledT = bufB + (size_t)NN * 64; // 64*512
    float* seqT = pooledT + 64 * GG;         // 128*512
    float* qkvT = seqT + DD * GG;            // 384*512
    float* aT   = qkvT + 3 * DD * GG;        // 128*512
    float* f1T  = aT + DD * GG;              // 512*512

    const int BS = 256;
    // CSR build
    hipMemsetAsync(cntN, 0, NN * sizeof(int), stream);
    k_ncount<<<EE / BS, BS, 0, stream>>>(edst, cntN);
    k_gsum<<<GG, 64, 0, stream>>>(cntN, gcnt);
    k_gprefix<<<1, GG, 0, stream>>>(gcnt, gbase);
    k_nscan<<<GG, BS, 0, stream>>>(cntN, gbase, node_off, cursorN);
    k_escatter<<<EE / BS, BS, 0, stream>>>(esrc, edst, cntN, cursorN, epackN);

    // GCN: agg-then-transform
    k_gcn1<<<GG, BS, 0, stream>>>(x, gW1, gb1, ln1g, ln1b, cntN, node_off, epackN, bufA);
    k_lin64<<<NN / 64, BS, 0, stream>>>(bufA, gW2, bufB);
    k_agg_ln<<<GG, BS, 0, stream>>>(bufB, cntN, node_off, epackN, gb2, ln2g, ln2b, bufA);
    k_agg_pool<<<GG, BS, 0, stream>>>(bufA, cntN, node_off, epackN, pooledT);
    k_emb<<<DD, GG, 0, stream>>>(pooledT, gW3, gb3, seqT);

    // Transformer (transposed activations)
    for (int l = 0; l < LL; l++) {
        k_gemmT<128, false, false><<<384, 128, 0, stream>>>(
            seqT, tWqkv + (size_t)l * 384 * 128, tbqkv + l * 384, nullptr, qkvT);
        k_attnT<<<BB * 4, TT, 0, stream>>>(qkvT, aT);
        k_gemmT<128, false, true><<<128, 128, 0, stream>>>(
            aT, tWo + (size_t)l * 128 * 128, tbo + l * 128, seqT, seqT);
        k_lnT<<<2, 256, 0, stream>>>(seqT, tg1 + l * 128, tb1 + l * 128);
        k_gemmT<128, true, false><<<512, 128, 0, stream>>>(
            seqT, tWf1 + (size_t)l * 512 * 128, tbf1 + l * 512, nullptr, f1T);
        k_gemmT<512, false, true><<<128, 128, 0, stream>>>(
            f1T, tWf2 + (size_t)l * 128 * 512, tbf2 + l * 128, seqT, seqT);
        k_lnT<<<2, 256, 0, stream>>>(seqT, tg2 + l * 128, tb2 + l * 128);
    }

    // head
    k_headT<<<BB, 128, 0, stream>>>(seqT, hW1, hb1, hW2, hb2, out);
}